// Round 3
// baseline (70.691 us; speedup 1.0000x reference)
//
#include <hip/hip_runtime.h>

// ProximityAwareLoss3Class, B=32, S=65536, C=3 — two-kernel, no spin.
//
// Serial structure reduces to per-sequence last-event max-scans (fwd, 6 ch:
// lastT1,T2,P1,P2,VP1,VP2 -> tm=(lastT2>lastT1), pm=(lastVP2>lastVP1) excl)
// and next-event min-scans (bwd, 4 ch: nextT1,T2,P1,P2, inclusive).
// Distances clamp at 255 (all proximity factors saturate by d>=25).
//
// K1: element-strided (dense loads), computes pred+CE once, writes one packed
//     u32/elem (bf16 CE | lab | pred) + per-1024-chunk 10-channel summaries.
// K2: contiguous per-thread runs; wave-0 prologue reduces the sequence's 64
//     chunk summaries into this chunk's prefix/suffix + any-flags; block-local
//     wave scans; FSM + proximity walk; ctr-based last-block deterministic
//     final mean. ctr cleared per call by a 4-byte memset node.

#define S_LEN 65536
#define BATCH 32
#define CHUNK 1024
#define NTH 256
#define PT 4                 // CHUNK / NTH
#define CPS 64               // chunks per sequence = S_LEN / CHUNK
#define NCH 2048             // BATCH * CPS
#define BIGI 0x3FFFFFFF

// ws layout (bytes)
#define WS_CTR    0          // 4
#define WS_SUMS   1024       // NCH * 12 * 4 = 98304 -> ends 99328
#define WS_PART   131072     // NCH * 2 * 8 = 32768 -> ends 163840
#define WS_PACKED 262144     // 2M * 4 = 8388608 -> ends 8650752

__global__ __launch_bounds__(NTH) void k1_ce(const float* __restrict__ logits,
                                             const int* __restrict__ labels,
                                             unsigned* __restrict__ packed,
                                             int* __restrict__ sums)
{
    const int chunkId = blockIdx.x;
    const int base = chunkId << 10;
    const int tid = threadIdx.x;
    const int lane = tid & 63, wid = tid >> 6;

    int iF[6] = {-1,-1,-1,-1,-1,-1};
    int iB[4] = {BIGI,BIGI,BIGI,BIGI};

    #pragma unroll
    for (int k = 0; k < PT; ++k) {
        const int e = base + (k << 8) + tid;          // element-strided: dense loads
        const float l0 = logits[3*e+0];
        const float l1 = logits[3*e+1];
        const float l2 = logits[3*e+2];
        const int   l  = labels[e];
        int p = 0; float bst = l0;
        if (l1 > bst) { p = 1; bst = l1; }
        if (l2 > bst) { p = 2; }
        const int lc = (l < 0) ? 3 : l;
        float ce = 0.0f;
        if (lc != 3) {
            const float mx  = fmaxf(l0, fmaxf(l1, l2));
            const float lse = mx + __logf(__expf(l0-mx) + __expf(l1-mx) + __expf(l2-mx));
            const float ly  = (lc == 0) ? l0 : ((lc == 1) ? l1 : l2);
            ce = -(ly - lse) * ((lc == 0) ? 1.0f : 30.0f);
        }
        unsigned u = __float_as_uint(ce);             // ce >= 0, RNE to bf16
        u += 0x7FFFu + ((u >> 16) & 1u);
        packed[e] = (u & 0xFFFF0000u) | (unsigned)((lc << 2) | p);

        const int pos = e & (S_LEN - 1);              // sequence-local position
        if (lc == 1) { iF[0] = max(iF[0], pos); iB[0] = min(iB[0], pos); }
        if (lc == 2) { iF[1] = max(iF[1], pos); iB[1] = min(iB[1], pos); }
        if (p  == 1) { iF[2] = max(iF[2], pos); iB[2] = min(iB[2], pos); }
        if (p  == 2) { iF[3] = max(iF[3], pos); iB[3] = min(iB[3], pos); }
        const bool valid = lc != 3;
        if (valid && p == 1) iF[4] = max(iF[4], pos);
        if (valid && p == 2) iF[5] = max(iF[5], pos);
    }

    __shared__ int wt[10][4];
    #pragma unroll
    for (int i = 0; i < 6; ++i) {
        int v = iF[i];
        #pragma unroll
        for (int o = 32; o; o >>= 1) v = max(v, __shfl_xor(v, o));
        if (lane == 0) wt[i][wid] = v;
    }
    #pragma unroll
    for (int i = 0; i < 4; ++i) {
        int v = iB[i];
        #pragma unroll
        for (int o = 32; o; o >>= 1) v = min(v, __shfl_xor(v, o));
        if (lane == 0) wt[6 + i][wid] = v;
    }
    __syncthreads();
    if (tid == 0) {
        int* dst = sums + chunkId * 12;
        #pragma unroll
        for (int i = 0; i < 6; ++i)
            dst[i] = max(max(wt[i][0], wt[i][1]), max(wt[i][2], wt[i][3]));
        #pragma unroll
        for (int i = 0; i < 4; ++i)
            dst[6+i] = min(min(wt[6+i][0], wt[6+i][1]), min(wt[6+i][2], wt[6+i][3]));
        dst[10] = 0; dst[11] = 0;
    }
}

__global__ __launch_bounds__(NTH) void k2_walk(const unsigned* __restrict__ packed,
                                               const int* __restrict__ sums,
                                               int* __restrict__ ctr,
                                               double* __restrict__ partials,
                                               float* __restrict__ out)
{
    const int chunkId = blockIdx.x;
    const int seq = chunkId >> 6;
    const int cs  = chunkId & (CPS - 1);
    const int tid = threadIdx.x;
    const int lane = tid & 63, wid = tid >> 6;
    const int posBase = cs * CHUNK + tid * PT;        // sequence-local

    // ---- prologue (wave 0): cross-chunk prefix/suffix + any flags ----
    __shared__ int pro[14];                           // inL[6], inN[4], any[4]
    if (tid < 64) {
        const int4* sp = (const int4*)(sums + ((seq << 6) + tid) * 12);
        const int4 a = sp[0], b = sp[1], c4 = sp[2];
        const int v[10] = {a.x,a.y,a.z,a.w,b.x,b.y,b.z,b.w,c4.x,c4.y};
        #pragma unroll
        for (int i = 0; i < 6; ++i) {
            int m = (tid < cs) ? v[i] : -1;
            #pragma unroll
            for (int o = 32; o; o >>= 1) m = max(m, __shfl_xor(m, o));
            if (tid == 0) pro[i] = m;
        }
        #pragma unroll
        for (int i = 0; i < 4; ++i) {
            int m = (tid > cs) ? v[6+i] : BIGI;
            #pragma unroll
            for (int o = 32; o; o >>= 1) m = min(m, __shfl_xor(m, o));
            if (tid == 0) pro[6+i] = m;
        }
        #pragma unroll
        for (int i = 0; i < 4; ++i) {
            int m = v[i];
            #pragma unroll
            for (int o = 32; o; o >>= 1) m = max(m, __shfl_xor(m, o));
            if (tid == 0) pro[10+i] = (m >= 0) ? 1 : 0;
        }
    }

    // ---- load packed (one uint4 per thread, coalesced) ----
    unsigned pk[PT];
    {
        const uint4* pp = (const uint4*)(packed + ((long long)chunkId << 10) + (tid << 2));
        const uint4 v = *pp;
        pk[0] = v.x; pk[1] = v.y; pk[2] = v.z; pk[3] = v.w;
    }

    // ---- thread-local scan summaries over contiguous 4 elems ----
    int iF[6] = {-1,-1,-1,-1,-1,-1};
    int iB[4] = {BIGI,BIGI,BIGI,BIGI};
    #pragma unroll
    for (int j = 0; j < PT; ++j) {
        const int p = pk[j] & 3, lc = (pk[j] >> 2) & 3;
        const int pos = posBase + j;
        if (lc == 1) iF[0] = pos;
        if (lc == 2) iF[1] = pos;
        if (p  == 1) iF[2] = pos;
        if (p  == 2) iF[3] = pos;
        const bool valid = lc != 3;
        if (valid && p == 1) iF[4] = pos;
        if (valid && p == 2) iF[5] = pos;
    }
    #pragma unroll
    for (int j = PT - 1; j >= 0; --j) {               // descending keeps smallest
        const int p = pk[j] & 3, lc = (pk[j] >> 2) & 3;
        const int pos = posBase + j;
        if (lc == 1) iB[0] = pos;
        if (lc == 2) iB[1] = pos;
        if (p  == 1) iB[2] = pos;
        if (p  == 2) iB[3] = pos;
    }

    // ---- wave inclusive scans ----
    #pragma unroll
    for (int i = 0; i < 6; ++i) {
        int v = iF[i];
        #pragma unroll
        for (int o = 1; o < 64; o <<= 1) {
            const int t = __shfl_up(v, o);
            if (lane >= o) v = max(v, t);
        }
        iF[i] = v;
    }
    #pragma unroll
    for (int i = 0; i < 4; ++i) {
        int v = iB[i];
        #pragma unroll
        for (int o = 1; o < 64; o <<= 1) {
            const int t = __shfl_down(v, o);
            if (lane + o < 64) v = min(v, t);
        }
        iB[i] = v;
    }

    __shared__ int wtF[6][4];
    __shared__ int wtB[4][4];
    if (lane == 63) {
        #pragma unroll
        for (int i = 0; i < 6; ++i) wtF[i][wid] = iF[i];
    }
    if (lane == 0) {
        #pragma unroll
        for (int i = 0; i < 4; ++i) wtB[i][wid] = iB[i];
    }
    __syncthreads();

    // ---- per-thread exclusive carries ----
    int exF[6], exB[4];
    #pragma unroll
    for (int i = 0; i < 6; ++i) {
        int carry = pro[i];
        #pragma unroll
        for (int w = 0; w < 3; ++w)
            if (w < wid) carry = max(carry, wtF[i][w]);
        const int t = __shfl_up(iF[i], 1);
        exF[i] = (lane > 0) ? max(carry, t) : carry;
    }
    #pragma unroll
    for (int i = 0; i < 4; ++i) {
        int carry = pro[6+i];
        #pragma unroll
        for (int w = 1; w < 4; ++w)
            if (w > wid) carry = min(carry, wtB[i][w]);
        const int t = __shfl_down(iB[i], 1);
        exB[i] = (lane < 63) ? min(carry, t) : carry;
    }

    // ---- backward walk: packed next-distances ----
    unsigned nd[PT];
    {
        int n1 = exB[0], n2 = exB[1], n3 = exB[2], n4 = exB[3];
        #pragma unroll
        for (int j = PT - 1; j >= 0; --j) {
            const int p = pk[j] & 3, lc = (pk[j] >> 2) & 3;
            const int pos = posBase + j;
            if (lc == 1) n1 = pos;
            if (lc == 2) n2 = pos;
            if (p  == 1) n3 = pos;
            if (p  == 2) n4 = pos;
            nd[j] = (unsigned)min(n1 - pos, 255)
                  | ((unsigned)min(n2 - pos, 255) << 8)
                  | ((unsigned)min(n3 - pos, 255) << 16)
                  | ((unsigned)min(n4 - pos, 255) << 24);
        }
    }

    // ---- forward walk: FSM + proximity factors + accumulate ----
    const int aT1 = pro[10], aT2 = pro[11], aP1 = pro[12], aP2 = pro[13];
    double sumAdj = 0.0;
    int vcount = 0;
    {
        int lT1 = exF[0], lT2 = exF[1], lP1 = exF[2], lP2 = exF[3], lV1 = exF[4], lV2 = exF[5];
        #pragma unroll
        for (int j = 0; j < PT; ++j) {
            const int p = pk[j] & 3, lc = (pk[j] >> 2) & 3;
            const float ce = __uint_as_float(pk[j] & 0xFFFF0000u);
            const bool valid = lc != 3;
            const int pos = posBase + j;
            const int tm = (lT2 > lT1) ? 1 : 0;       // exclusive state
            const int pm = (lV2 > lV1) ? 1 : 0;
            float m = 1.0f;
            if (valid && p == 1 && pm == 0) m *= 100.0f;
            if (valid && p == 2 && pm == 1) m *= 100.0f;
            if (lc == 1 && tm == 1 && p == 1) m *= 0.1f;
            if (lc == 2 && tm == 0 && p == 2) m *= 0.1f;
            if (lc == 1) lT1 = pos;
            if (lc == 2) lT2 = pos;
            if (p  == 1) lP1 = pos;
            if (p  == 2) lP2 = pos;
            if (valid && p == 1) lV1 = pos;
            if (valid && p == 2) lV2 = pos;

            const int dpT1 = (lT1 >= 0) ? min(pos - lT1, 255) : 255;
            const int dpT2 = (lT2 >= 0) ? min(pos - lT2, 255) : 255;
            const int dpP1 = (lP1 >= 0) ? min(pos - lP1, 255) : 255;
            const int dpP2 = (lP2 >= 0) ? min(pos - lP2, 255) : 255;
            const unsigned ndj = nd[j];
            const int d2t1 = min(dpT1, (int)( ndj        & 255u));
            const int d2t2 = min(dpT2, (int)((ndj >> 8)  & 255u));
            const int d2p1 = min(dpP1, (int)((ndj >> 16) & 255u));
            const int d2p2 = min(dpP2, (int)((ndj >> 24) & 255u));

            if (p == 1) m *= aT1 ? ((d2t1 == 0) ? 0.1f : ((d2t1 <= 5) ? (0.1f + (float)d2t1 * 0.18f) : 10.0f)) : 20.0f;
            if (p == 2) m *= aT2 ? ((d2t2 == 0) ? 0.1f : ((d2t2 <= 5) ? (0.1f + (float)d2t2 * 0.18f) : 10.0f)) : 20.0f;
            if (lc == 1) m *= aP1 ? ((d2p1 > 5) ? fminf(2.0f + (float)(d2p1 - 5) * 0.3f, 8.0f) : 1.0f) : 5.0f;
            if (lc == 2) m *= aP2 ? ((d2p2 > 5) ? fminf(2.0f + (float)(d2p2 - 5) * 0.3f, 8.0f) : 1.0f) : 5.0f;

            sumAdj += (double)(ce * m);
            vcount += valid ? 1 : 0;
        }
    }

    // ---- block reduce + last-block deterministic final ----
    double sA = sumAdj, sV = (double)vcount;
    #pragma unroll
    for (int o = 32; o > 0; o >>= 1) {
        sA += __shfl_down(sA, o);
        sV += __shfl_down(sV, o);
    }
    __shared__ double rr[2][4];
    __shared__ int isLast;
    if (lane == 0) { rr[0][wid] = sA; rr[1][wid] = sV; }
    __syncthreads();
    if (tid == 0) {
        const double a = rr[0][0] + rr[0][1] + rr[0][2] + rr[0][3];
        const double v = rr[1][0] + rr[1][1] + rr[1][2] + rr[1][3];
        __hip_atomic_store(&partials[2*chunkId+0], a, __ATOMIC_RELAXED, __HIP_MEMORY_SCOPE_AGENT);
        __hip_atomic_store(&partials[2*chunkId+1], v, __ATOMIC_RELAXED, __HIP_MEMORY_SCOPE_AGENT);
        const int old = __hip_atomic_fetch_add(ctr, 1, __ATOMIC_ACQ_REL, __HIP_MEMORY_SCOPE_AGENT);
        isLast = (old == NCH - 1) ? 1 : 0;
    }
    __syncthreads();
    if (isLast) {
        double tA = 0.0, tV = 0.0;
        for (int i = tid; i < NCH; i += NTH) {        // fixed order -> deterministic
            tA += __hip_atomic_load(&partials[2*i+0], __ATOMIC_RELAXED, __HIP_MEMORY_SCOPE_AGENT);
            tV += __hip_atomic_load(&partials[2*i+1], __ATOMIC_RELAXED, __HIP_MEMORY_SCOPE_AGENT);
        }
        #pragma unroll
        for (int o = 32; o > 0; o >>= 1) {
            tA += __shfl_down(tA, o);
            tV += __shfl_down(tV, o);
        }
        __syncthreads();
        if (lane == 0) { rr[0][wid] = tA; rr[1][wid] = tV; }
        __syncthreads();
        if (tid == 0) {
            const double A = rr[0][0] + rr[0][1] + rr[0][2] + rr[0][3];
            const double V = rr[1][0] + rr[1][1] + rr[1][2] + rr[1][3];
            out[0] = (float)(A / fmax(V, 1.0));
        }
    }
}

extern "C" void kernel_launch(void* const* d_in, const int* in_sizes, int n_in,
                              void* d_out, int out_size, void* d_ws, size_t ws_size,
                              hipStream_t stream) {
    const float* logits = (const float*)d_in[0];
    const int*   labels = (const int*)d_in[1];
    float* out = (float*)d_out;
    char* ws = (char*)d_ws;

    int*      ctr    = (int*)(ws + WS_CTR);
    int*      sums   = (int*)(ws + WS_SUMS);
    double*   parts  = (double*)(ws + WS_PART);
    unsigned* packed = (unsigned*)(ws + WS_PACKED);

    hipMemsetAsync(ctr, 0, 4, stream);   // ws not re-poisoned between replays
    k1_ce<<<NCH, NTH, 0, stream>>>(logits, labels, packed, sums);
    k2_walk<<<NCH, NTH, 0, stream>>>(packed, sums, ctr, parts, out);
}

// Round 4
// 50.150 us; speedup vs baseline: 1.4096x; 1.4096x over previous
//
#include <hip/hip_runtime.h>

// ProximityAwareLoss3Class, B=32, S=65536, C=3 — two kernels, long per-thread runs.
//
// Serial structure reduces to per-sequence last-event max-scans (fwd, 6 ch:
// lastT1,T2,P1,P2,VP1,VP2 -> tm=(lastT2>lastT1), pm=(lastVP2>lastVP1) excl)
// and next-event min-scans (bwd, 4 ch: nextT1,T2,P1,P2, inclusive).
// Distances clamp at 255 (all proximity factors saturate by d>=25).
//
// Round-3 lesson: K2 was shuffle-latency bound (PT=4 -> ~60 dependent DS ops
// per 4 elements, 2048 blocks). Now PT2=32, 256 blocks: same scan cost serves
// 8x the elements, 8x less total shuffle traffic. K1 uses contiguous PT=8
// with float4/int4/uint4 vector memory ops.
//
// K1: computes pred+CE once, writes packed u32/elem (bf16 CE | lab | pred) +
//     per-2048-elem 10-channel summaries (1024 blocks).
// K2: 256 blocks x 8192-elem chunks; half-wave prologue reduces the seq's 32
//     K1 summaries into prefix/suffix/any; block scans; FSM+proximity walk;
//     ctr-based last-block deterministic final mean (ctr memset per call).

#define S_LEN 65536
#define BATCH 32
#define BIGI 0x3FFFFFFF

#define NTH1 256
#define PT1 8
#define CHUNK1 2048          // NTH1*PT1
#define CPS1 32              // S_LEN/CHUNK1
#define NCH1 1024            // BATCH*CPS1

#define NTH2 256
#define PT2 32
#define CHUNK2 8192          // NTH2*PT2
#define CPS2 8               // S_LEN/CHUNK2
#define NCH2 256             // BATCH*CPS2

// ws layout (bytes)
#define WS_CTR    0          // 4
#define WS_SUMS   1024       // NCH1 * 12 * 4 = 49152 -> ends 50176
#define WS_PART   65536      // NCH2 * 2 * 8 = 4096  -> ends 69632
#define WS_PACKED 131072     // 2M * 4 = 8388608

__global__ __launch_bounds__(NTH1) void k1_ce(const float* __restrict__ logits,
                                              const int* __restrict__ labels,
                                              unsigned* __restrict__ packed,
                                              int* __restrict__ sums)
{
    const int chunkId = blockIdx.x;
    const int tid = threadIdx.x;
    const int lane = tid & 63, wid = tid >> 6;
    const long long e0 = ((long long)chunkId << 11) + tid * PT1;
    const int posBase = (int)(e0 & (S_LEN - 1));     // sequence-local

    float f[3 * PT1];
    {
        const float4* fp = (const float4*)(logits + 3 * e0);
        #pragma unroll
        for (int i = 0; i < 6; ++i) {
            const float4 v = fp[i];
            f[4*i+0]=v.x; f[4*i+1]=v.y; f[4*i+2]=v.z; f[4*i+3]=v.w;
        }
    }
    int lb[PT1];
    {
        const int4* lp = (const int4*)(labels + e0);
        const int4 a = lp[0], b = lp[1];
        lb[0]=a.x; lb[1]=a.y; lb[2]=a.z; lb[3]=a.w;
        lb[4]=b.x; lb[5]=b.y; lb[6]=b.z; lb[7]=b.w;
    }

    unsigned pk[PT1];
    int iF[6] = {-1,-1,-1,-1,-1,-1};
    int iB[4] = {BIGI,BIGI,BIGI,BIGI};
    #pragma unroll
    for (int j = 0; j < PT1; ++j) {
        const float l0 = f[3*j], l1 = f[3*j+1], l2 = f[3*j+2];
        int p = 0; float bst = l0;
        if (l1 > bst) { p = 1; bst = l1; }
        if (l2 > bst) { p = 2; }
        const int l  = lb[j];
        const int lc = (l < 0) ? 3 : l;
        float ce = 0.0f;
        if (lc != 3) {
            const float mx  = fmaxf(l0, fmaxf(l1, l2));
            const float lse = mx + __logf(__expf(l0-mx) + __expf(l1-mx) + __expf(l2-mx));
            const float ly  = (lc == 0) ? l0 : ((lc == 1) ? l1 : l2);
            ce = -(ly - lse) * ((lc == 0) ? 1.0f : 30.0f);
        }
        unsigned u = __float_as_uint(ce);            // ce >= 0, RNE to bf16
        u += 0x7FFFu + ((u >> 16) & 1u);
        pk[j] = (u & 0xFFFF0000u) | (unsigned)((lc << 2) | p);

        const int pos = posBase + j;                 // ascending: overwrite = last
        if (lc == 1) { iF[0] = pos; iB[0] = min(iB[0], pos); }
        if (lc == 2) { iF[1] = pos; iB[1] = min(iB[1], pos); }
        if (p  == 1) { iF[2] = pos; iB[2] = min(iB[2], pos); }
        if (p  == 2) { iF[3] = pos; iB[3] = min(iB[3], pos); }
        const bool valid = lc != 3;
        if (valid && p == 1) iF[4] = pos;
        if (valid && p == 2) iF[5] = pos;
    }
    {
        uint4* op = (uint4*)(packed + e0);
        op[0] = make_uint4(pk[0], pk[1], pk[2], pk[3]);
        op[1] = make_uint4(pk[4], pk[5], pk[6], pk[7]);
    }

    __shared__ int wt[10][4];
    #pragma unroll
    for (int i = 0; i < 6; ++i) {
        int v = iF[i];
        #pragma unroll
        for (int o = 32; o; o >>= 1) v = max(v, __shfl_xor(v, o));
        if (lane == 0) wt[i][wid] = v;
    }
    #pragma unroll
    for (int i = 0; i < 4; ++i) {
        int v = iB[i];
        #pragma unroll
        for (int o = 32; o; o >>= 1) v = min(v, __shfl_xor(v, o));
        if (lane == 0) wt[6 + i][wid] = v;
    }
    __syncthreads();
    if (tid == 0) {
        int* dst = sums + chunkId * 12;
        #pragma unroll
        for (int i = 0; i < 6; ++i)
            dst[i] = max(max(wt[i][0], wt[i][1]), max(wt[i][2], wt[i][3]));
        #pragma unroll
        for (int i = 0; i < 4; ++i)
            dst[6+i] = min(min(wt[6+i][0], wt[6+i][1]), min(wt[6+i][2], wt[6+i][3]));
        dst[10] = 0; dst[11] = 0;
    }
}

__global__ __launch_bounds__(NTH2) void k2_walk(const unsigned* __restrict__ packed,
                                                const int* __restrict__ sums,
                                                int* __restrict__ ctr,
                                                double* __restrict__ partials,
                                                float* __restrict__ out)
{
    const int chunkId = blockIdx.x;                  // 0..255
    const int seq = chunkId >> 3;
    const int cs  = chunkId & (CPS2 - 1);
    const int tid = threadIdx.x;
    const int lane = tid & 63, wid = tid >> 6;
    const int posBase = cs * CHUNK2 + tid * PT2;     // sequence-local

    // ---- prologue (half-wave): cross-chunk prefix/suffix + any flags ----
    __shared__ int pro[14];                          // inL[6], inN[4], any[4]
    if (tid < CPS1) {
        const int4* sp = (const int4*)(sums + ((seq << 5) + tid) * 12);
        const int4 a = sp[0], b = sp[1], c4 = sp[2];
        const int v[10] = {a.x,a.y,a.z,a.w,b.x,b.y,b.z,b.w,c4.x,c4.y};
        const int k1lo = cs << 2;                    // K1 chunks [k1lo, k1lo+4) are ours
        #pragma unroll
        for (int i = 0; i < 6; ++i) {
            int m = (tid < k1lo) ? v[i] : -1;
            #pragma unroll
            for (int o = 16; o; o >>= 1) m = max(m, __shfl_xor(m, o));
            if (tid == 0) pro[i] = m;
        }
        #pragma unroll
        for (int i = 0; i < 4; ++i) {
            int m = (tid >= k1lo + 4) ? v[6+i] : BIGI;
            #pragma unroll
            for (int o = 16; o; o >>= 1) m = min(m, __shfl_xor(m, o));
            if (tid == 0) pro[6+i] = m;
        }
        #pragma unroll
        for (int i = 0; i < 4; ++i) {
            int m = v[i];
            #pragma unroll
            for (int o = 16; o; o >>= 1) m = max(m, __shfl_xor(m, o));
            if (tid == 0) pro[10+i] = (m >= 0) ? 1 : 0;
        }
    }

    // ---- load packed (8 x uint4, contiguous 128B per thread) ----
    unsigned pk[PT2];
    {
        const uint4* pp = (const uint4*)(packed + ((long long)chunkId << 13) + tid * PT2);
        #pragma unroll
        for (int k = 0; k < 8; ++k) {
            const uint4 v = pp[k];
            pk[4*k+0]=v.x; pk[4*k+1]=v.y; pk[4*k+2]=v.z; pk[4*k+3]=v.w;
        }
    }

    // ---- thread-local scan summaries ----
    int iF[6] = {-1,-1,-1,-1,-1,-1};
    int iB[4] = {BIGI,BIGI,BIGI,BIGI};
    #pragma unroll
    for (int j = 0; j < PT2; ++j) {
        const int p = pk[j] & 3, lc = (pk[j] >> 2) & 3;
        const int pos = posBase + j;
        if (lc == 1) iF[0] = pos;
        if (lc == 2) iF[1] = pos;
        if (p  == 1) iF[2] = pos;
        if (p  == 2) iF[3] = pos;
        const bool valid = lc != 3;
        if (valid && p == 1) iF[4] = pos;
        if (valid && p == 2) iF[5] = pos;
    }
    #pragma unroll
    for (int j = PT2 - 1; j >= 0; --j) {             // descending keeps smallest
        const int p = pk[j] & 3, lc = (pk[j] >> 2) & 3;
        const int pos = posBase + j;
        if (lc == 1) iB[0] = pos;
        if (lc == 2) iB[1] = pos;
        if (p  == 1) iB[2] = pos;
        if (p  == 2) iB[3] = pos;
    }

    // ---- wave inclusive scans ----
    #pragma unroll
    for (int i = 0; i < 6; ++i) {
        int v = iF[i];
        #pragma unroll
        for (int o = 1; o < 64; o <<= 1) {
            const int t = __shfl_up(v, o);
            if (lane >= o) v = max(v, t);
        }
        iF[i] = v;
    }
    #pragma unroll
    for (int i = 0; i < 4; ++i) {
        int v = iB[i];
        #pragma unroll
        for (int o = 1; o < 64; o <<= 1) {
            const int t = __shfl_down(v, o);
            if (lane + o < 64) v = min(v, t);
        }
        iB[i] = v;
    }

    __shared__ int wtF[6][4];
    __shared__ int wtB[4][4];
    if (lane == 63) {
        #pragma unroll
        for (int i = 0; i < 6; ++i) wtF[i][wid] = iF[i];
    }
    if (lane == 0) {
        #pragma unroll
        for (int i = 0; i < 4; ++i) wtB[i][wid] = iB[i];
    }
    __syncthreads();

    // ---- per-thread exclusive carries ----
    int exF[6], exB[4];
    #pragma unroll
    for (int i = 0; i < 6; ++i) {
        int carry = pro[i];
        #pragma unroll
        for (int w = 0; w < 3; ++w)
            if (w < wid) carry = max(carry, wtF[i][w]);
        const int t = __shfl_up(iF[i], 1);
        exF[i] = (lane > 0) ? max(carry, t) : carry;
    }
    #pragma unroll
    for (int i = 0; i < 4; ++i) {
        int carry = pro[6+i];
        #pragma unroll
        for (int w = 1; w < 4; ++w)
            if (w > wid) carry = min(carry, wtB[i][w]);
        const int t = __shfl_down(iB[i], 1);
        exB[i] = (lane < 63) ? min(carry, t) : carry;
    }

    // ---- backward walk: packed next-distances ----
    unsigned nd[PT2];
    {
        int n1 = exB[0], n2 = exB[1], n3 = exB[2], n4 = exB[3];
        #pragma unroll
        for (int j = PT2 - 1; j >= 0; --j) {
            const int p = pk[j] & 3, lc = (pk[j] >> 2) & 3;
            const int pos = posBase + j;
            if (lc == 1) n1 = pos;
            if (lc == 2) n2 = pos;
            if (p  == 1) n3 = pos;
            if (p  == 2) n4 = pos;
            nd[j] = (unsigned)min(n1 - pos, 255)
                  | ((unsigned)min(n2 - pos, 255) << 8)
                  | ((unsigned)min(n3 - pos, 255) << 16)
                  | ((unsigned)min(n4 - pos, 255) << 24);
        }
    }

    // ---- forward walk: FSM + proximity factors + accumulate ----
    const int aT1 = pro[10], aT2 = pro[11], aP1 = pro[12], aP2 = pro[13];
    double sumAdj = 0.0;
    int vcount = 0;
    {
        int lT1 = exF[0], lT2 = exF[1], lP1 = exF[2], lP2 = exF[3], lV1 = exF[4], lV2 = exF[5];
        #pragma unroll
        for (int j = 0; j < PT2; ++j) {
            const int p = pk[j] & 3, lc = (pk[j] >> 2) & 3;
            const float ce = __uint_as_float(pk[j] & 0xFFFF0000u);
            const bool valid = lc != 3;
            const int pos = posBase + j;
            const int tm = (lT2 > lT1) ? 1 : 0;      // exclusive state
            const int pm = (lV2 > lV1) ? 1 : 0;
            float m = 1.0f;
            if (valid && p == 1 && pm == 0) m *= 100.0f;
            if (valid && p == 2 && pm == 1) m *= 100.0f;
            if (lc == 1 && tm == 1 && p == 1) m *= 0.1f;
            if (lc == 2 && tm == 0 && p == 2) m *= 0.1f;
            if (lc == 1) lT1 = pos;
            if (lc == 2) lT2 = pos;
            if (p  == 1) lP1 = pos;
            if (p  == 2) lP2 = pos;
            if (valid && p == 1) lV1 = pos;
            if (valid && p == 2) lV2 = pos;

            const int dpT1 = (lT1 >= 0) ? min(pos - lT1, 255) : 255;
            const int dpT2 = (lT2 >= 0) ? min(pos - lT2, 255) : 255;
            const int dpP1 = (lP1 >= 0) ? min(pos - lP1, 255) : 255;
            const int dpP2 = (lP2 >= 0) ? min(pos - lP2, 255) : 255;
            const unsigned ndj = nd[j];
            const int d2t1 = min(dpT1, (int)( ndj        & 255u));
            const int d2t2 = min(dpT2, (int)((ndj >> 8)  & 255u));
            const int d2p1 = min(dpP1, (int)((ndj >> 16) & 255u));
            const int d2p2 = min(dpP2, (int)((ndj >> 24) & 255u));

            if (p == 1) m *= aT1 ? ((d2t1 == 0) ? 0.1f : ((d2t1 <= 5) ? (0.1f + (float)d2t1 * 0.18f) : 10.0f)) : 20.0f;
            if (p == 2) m *= aT2 ? ((d2t2 == 0) ? 0.1f : ((d2t2 <= 5) ? (0.1f + (float)d2t2 * 0.18f) : 10.0f)) : 20.0f;
            if (lc == 1) m *= aP1 ? ((d2p1 > 5) ? fminf(2.0f + (float)(d2p1 - 5) * 0.3f, 8.0f) : 1.0f) : 5.0f;
            if (lc == 2) m *= aP2 ? ((d2p2 > 5) ? fminf(2.0f + (float)(d2p2 - 5) * 0.3f, 8.0f) : 1.0f) : 5.0f;

            sumAdj += (double)(ce * m);
            vcount += valid ? 1 : 0;
        }
    }

    // ---- block reduce + last-block deterministic final ----
    double sA = sumAdj, sV = (double)vcount;
    #pragma unroll
    for (int o = 32; o > 0; o >>= 1) {
        sA += __shfl_down(sA, o);
        sV += __shfl_down(sV, o);
    }
    __shared__ double rr[2][4];
    __shared__ int isLast;
    if (lane == 0) { rr[0][wid] = sA; rr[1][wid] = sV; }
    __syncthreads();
    if (tid == 0) {
        const double a = rr[0][0] + rr[0][1] + rr[0][2] + rr[0][3];
        const double v = rr[1][0] + rr[1][1] + rr[1][2] + rr[1][3];
        __hip_atomic_store(&partials[2*chunkId+0], a, __ATOMIC_RELAXED, __HIP_MEMORY_SCOPE_AGENT);
        __hip_atomic_store(&partials[2*chunkId+1], v, __ATOMIC_RELAXED, __HIP_MEMORY_SCOPE_AGENT);
        const int old = __hip_atomic_fetch_add(ctr, 1, __ATOMIC_ACQ_REL, __HIP_MEMORY_SCOPE_AGENT);
        isLast = (old == NCH2 - 1) ? 1 : 0;
    }
    __syncthreads();
    if (isLast) {
        double tA = 0.0, tV = 0.0;
        for (int i = tid; i < NCH2; i += NTH2) {     // fixed order -> deterministic
            tA += __hip_atomic_load(&partials[2*i+0], __ATOMIC_RELAXED, __HIP_MEMORY_SCOPE_AGENT);
            tV += __hip_atomic_load(&partials[2*i+1], __ATOMIC_RELAXED, __HIP_MEMORY_SCOPE_AGENT);
        }
        #pragma unroll
        for (int o = 32; o > 0; o >>= 1) {
            tA += __shfl_down(tA, o);
            tV += __shfl_down(tV, o);
        }
        __syncthreads();
        if (lane == 0) { rr[0][wid] = tA; rr[1][wid] = tV; }
        __syncthreads();
        if (tid == 0) {
            const double A = rr[0][0] + rr[0][1] + rr[0][2] + rr[0][3];
            const double V = rr[1][0] + rr[1][1] + rr[1][2] + rr[1][3];
            out[0] = (float)(A / fmax(V, 1.0));
        }
    }
}

extern "C" void kernel_launch(void* const* d_in, const int* in_sizes, int n_in,
                              void* d_out, int out_size, void* d_ws, size_t ws_size,
                              hipStream_t stream) {
    const float* logits = (const float*)d_in[0];
    const int*   labels = (const int*)d_in[1];
    float* out = (float*)d_out;
    char* ws = (char*)d_ws;

    int*      ctr    = (int*)(ws + WS_CTR);
    int*      sums   = (int*)(ws + WS_SUMS);
    double*   parts  = (double*)(ws + WS_PART);
    unsigned* packed = (unsigned*)(ws + WS_PACKED);

    hipMemsetAsync(ctr, 0, 4, stream);   // ws not re-poisoned between replays
    k1_ce<<<NCH1, NTH1, 0, stream>>>(logits, labels, packed, sums);
    k2_walk<<<NCH2, NTH2, 0, stream>>>(packed, sums, ctr, parts, out);
}

// Round 5
// 37.745 us; speedup vs baseline: 1.8728x; 1.3287x over previous
//
#include <hip/hip_runtime.h>

// ProximityAwareLoss3Class, B=32, S=65536, C=3.
// R1's proven 4-kernel structure (37.8us) + the packed intermediate from R3/R4.
// Lesson R2-R4: __shfl-based scans/prologues are the slow path on gfx950
// (ds_bpermute chains); R1's LDS Hillis-Steele scans were fast. All cross-
// thread scans here are LDS-based; zero __shfl in hot kernels.
//
// Serial structure reduces to per-sequence last-event max-scans (fwd, 6 ch:
// lastT1,T2,P1,P2,VP1,VP2 -> tm=(lastT2>lastT1), pm=(lastVP2>lastVP1) excl)
// and next-event min-scans (bwd, 4 ch: nextT1,T2,P1,P2, inclusive).
// Distances clamp at 255 (factors saturate by d>=25).
//
// K1: reads logits+labels once (contiguous float4/int4), computes pred+CE,
//     writes packed u32/elem (bf16 CE | labcode | pred) + per-chunk 10-ch
//     summaries (LDS tree reduce).
// K2: tiny serial cross-chunk combine (32 seqs x 32 chunks) -> per-chunk
//     incoming prefix/suffix + any-flags.
// K3: per-chunk pass reading packed; LDS Hillis-Steele block scans; FSM +
//     proximity walk; per-chunk double partials.
// K4: final deterministic reduce -> mean.

#define S_LEN 65536
#define BATCH 32
#define CHUNK 2048
#define NTHREADS 256
#define PER_THREAD 8            // CHUNK / NTHREADS
#define CHUNKS_PER_SEQ 32       // S_LEN / CHUNK
#define NCHUNK 1024             // BATCH * CHUNKS_PER_SEQ
#define BIGI 0x3FFFFFFF

struct ChunkSum { int mx[6]; int mn[4]; };   // last T1,T2,P1,P2,VP1,VP2 | first T1,T2,P1,P2
struct ChunkIn  { int inLast[6]; int inNext[4]; };

// ws layout (bytes)
#define WS_SUMS   0
#define WS_INS    (NCHUNK * (int)sizeof(ChunkSum))            // 40960
#define WS_FLAGS  (WS_INS + NCHUNK * (int)sizeof(ChunkIn))    // 81920
#define WS_PART   (WS_FLAGS + BATCH * 4 * 4)                  // 82432 (8-aligned)
#define WS_PACKED (WS_PART + NCHUNK * 2 * 8)                  // 98816 (16-aligned)
// total = 98816 + 2M*4 = 8487424 bytes

__global__ __launch_bounds__(NTHREADS) void k1_summ(const float* __restrict__ logits,
                                                    const int* __restrict__ labels,
                                                    unsigned* __restrict__ packed,
                                                    ChunkSum* __restrict__ sums) {
    const int chunkId = blockIdx.x;
    const int seq = chunkId / CHUNKS_PER_SEQ;
    const int cs  = chunkId % CHUNKS_PER_SEQ;
    const int tid = threadIdx.x;
    const int posBase = cs * CHUNK + tid * PER_THREAD;   // sequence-local position
    const int e0 = seq * S_LEN + posBase;

    int lab[PER_THREAD];
    {
        const int4* lp = (const int4*)(labels + e0);
        int4 a = lp[0], b = lp[1];
        lab[0]=a.x; lab[1]=a.y; lab[2]=a.z; lab[3]=a.w;
        lab[4]=b.x; lab[5]=b.y; lab[6]=b.z; lab[7]=b.w;
    }
    float f[3 * PER_THREAD];
    {
        const float4* fp = (const float4*)(logits + 3ll * e0);
        #pragma unroll
        for (int i = 0; i < 6; ++i) {
            float4 v = fp[i];
            f[4*i+0]=v.x; f[4*i+1]=v.y; f[4*i+2]=v.z; f[4*i+3]=v.w;
        }
    }
    unsigned pk[PER_THREAD];
    int mx[6] = {-1,-1,-1,-1,-1,-1};
    int mn[4] = {BIGI,BIGI,BIGI,BIGI};
    #pragma unroll
    for (int j = 0; j < PER_THREAD; ++j) {
        const float l0 = f[3*j], l1 = f[3*j+1], l2 = f[3*j+2];
        int p = 0; float bst = l0;
        if (l1 > bst) { p = 1; bst = l1; }
        if (l2 > bst) { p = 2; }
        const int l  = lab[j];
        const int lc = (l < 0) ? 3 : l;
        float ce = 0.0f;
        if (lc != 3) {
            const float mxv = fmaxf(l0, fmaxf(l1, l2));
            const float lse = mxv + __logf(__expf(l0-mxv) + __expf(l1-mxv) + __expf(l2-mxv));
            const float ly  = (lc == 0) ? l0 : ((lc == 1) ? l1 : l2);
            ce = -(ly - lse) * ((lc == 0) ? 1.0f : 30.0f);   // class_weights [1,30,30]
        }
        unsigned u = __float_as_uint(ce);                    // ce >= 0, RNE to bf16
        u += 0x7FFFu + ((u >> 16) & 1u);
        pk[j] = (u & 0xFFFF0000u) | (unsigned)((lc << 2) | p);

        const int pos = posBase + j;                          // ascending: overwrite = last
        if (lc == 1) { mx[0] = pos; mn[0] = min(mn[0], pos); }
        if (lc == 2) { mx[1] = pos; mn[1] = min(mn[1], pos); }
        if (p  == 1) { mx[2] = pos; mn[2] = min(mn[2], pos); }
        if (p  == 2) { mx[3] = pos; mn[3] = min(mn[3], pos); }
        const bool valid = lc != 3;
        if (valid && p == 1) mx[4] = pos;
        if (valid && p == 2) mx[5] = pos;
    }
    {
        uint4* op = (uint4*)(packed + e0);
        op[0] = make_uint4(pk[0], pk[1], pk[2], pk[3]);
        op[1] = make_uint4(pk[4], pk[5], pk[6], pk[7]);
    }

    __shared__ int sF[6][NTHREADS];
    __shared__ int sB[4][NTHREADS];
    #pragma unroll
    for (int i = 0; i < 6; ++i) sF[i][tid] = mx[i];
    #pragma unroll
    for (int i = 0; i < 4; ++i) sB[i][tid] = mn[i];
    __syncthreads();
    for (int st = NTHREADS / 2; st > 0; st >>= 1) {
        if (tid < st) {
            #pragma unroll
            for (int i = 0; i < 6; ++i) sF[i][tid] = max(sF[i][tid], sF[i][tid + st]);
            #pragma unroll
            for (int i = 0; i < 4; ++i) sB[i][tid] = min(sB[i][tid], sB[i][tid + st]);
        }
        __syncthreads();
    }
    if (tid == 0) {
        ChunkSum out;
        #pragma unroll
        for (int i = 0; i < 6; ++i) out.mx[i] = sF[i][0];
        #pragma unroll
        for (int i = 0; i < 4; ++i) out.mn[i] = sB[i][0];
        sums[chunkId] = out;
    }
}

__global__ __launch_bounds__(64) void k2_combine(const ChunkSum* __restrict__ sums,
                                                 ChunkIn* __restrict__ ins,
                                                 int* __restrict__ anyFlags) {
    const int s = threadIdx.x;
    if (s >= BATCH) return;
    int run[6] = {-1,-1,-1,-1,-1,-1};
    for (int k = 0; k < CHUNKS_PER_SEQ; ++k) {
        const int c = s * CHUNKS_PER_SEQ + k;
        #pragma unroll
        for (int i = 0; i < 6; ++i) ins[c].inLast[i] = run[i];
        #pragma unroll
        for (int i = 0; i < 6; ++i) run[i] = max(run[i], sums[c].mx[i]);
    }
    anyFlags[4*s+0] = (run[0] >= 0) ? 1 : 0;   // any true class1
    anyFlags[4*s+1] = (run[1] >= 0) ? 1 : 0;   // any true class2
    anyFlags[4*s+2] = (run[2] >= 0) ? 1 : 0;   // any pred class1
    anyFlags[4*s+3] = (run[3] >= 0) ? 1 : 0;   // any pred class2
    int rn[4] = {BIGI,BIGI,BIGI,BIGI};
    for (int k = CHUNKS_PER_SEQ - 1; k >= 0; --k) {
        const int c = s * CHUNKS_PER_SEQ + k;
        #pragma unroll
        for (int i = 0; i < 4; ++i) ins[c].inNext[i] = rn[i];
        #pragma unroll
        for (int i = 0; i < 4; ++i) rn[i] = min(rn[i], sums[c].mn[i]);
    }
}

__global__ __launch_bounds__(NTHREADS) void k3_main(const unsigned* __restrict__ packed,
                                                    const ChunkIn* __restrict__ ins,
                                                    const int* __restrict__ anyFlags,
                                                    double* __restrict__ partials) {
    const int chunkId = blockIdx.x;
    const int seq = chunkId / CHUNKS_PER_SEQ;
    const int cs  = chunkId % CHUNKS_PER_SEQ;
    const int tid = threadIdx.x;
    const int posBase = cs * CHUNK + tid * PER_THREAD;
    const int e0 = seq * S_LEN + posBase;

    unsigned pk[PER_THREAD];
    {
        const uint4* pp = (const uint4*)(packed + e0);
        const uint4 a = pp[0], b = pp[1];
        pk[0]=a.x; pk[1]=a.y; pk[2]=a.z; pk[3]=a.w;
        pk[4]=b.x; pk[5]=b.y; pk[6]=b.z; pk[7]=b.w;
    }

    // thread-local scan summaries
    int lmx[6] = {-1,-1,-1,-1,-1,-1};
    int lmn[4] = {BIGI,BIGI,BIGI,BIGI};
    #pragma unroll
    for (int j = 0; j < PER_THREAD; ++j) {
        const int p = pk[j] & 3, lc = (pk[j] >> 2) & 3;
        const int pos = posBase + j;
        if (lc == 1) lmx[0] = pos;
        if (lc == 2) lmx[1] = pos;
        if (p  == 1) lmx[2] = pos;
        if (p  == 2) lmx[3] = pos;
        const bool valid = lc != 3;
        if (valid && p == 1) lmx[4] = pos;
        if (valid && p == 2) lmx[5] = pos;
    }
    #pragma unroll
    for (int j = PER_THREAD - 1; j >= 0; --j) {          // descending keeps smallest
        const int p = pk[j] & 3, lc = (pk[j] >> 2) & 3;
        const int pos = posBase + j;
        if (lc == 1) lmn[0] = pos;
        if (lc == 2) lmn[1] = pos;
        if (p  == 1) lmn[2] = pos;
        if (p  == 2) lmn[3] = pos;
    }

    __shared__ int sF[6][NTHREADS];
    __shared__ int sB[4][NTHREADS];
    #pragma unroll
    for (int i = 0; i < 6; ++i) sF[i][tid] = lmx[i];
    #pragma unroll
    for (int i = 0; i < 4; ++i) sB[i][tid] = lmn[i];
    __syncthreads();
    // Hillis-Steele: inclusive max-scan (fwd) + inclusive min-scan (bwd), LDS-based
    for (int st = 1; st < NTHREADS; st <<= 1) {
        int vF[6], vB[4];
        const bool doF = (tid >= st);
        const bool doB = (tid + st < NTHREADS);
        if (doF) {
            #pragma unroll
            for (int i = 0; i < 6; ++i) vF[i] = max(sF[i][tid], sF[i][tid - st]);
        }
        if (doB) {
            #pragma unroll
            for (int i = 0; i < 4; ++i) vB[i] = min(sB[i][tid], sB[i][tid + st]);
        }
        __syncthreads();
        if (doF) {
            #pragma unroll
            for (int i = 0; i < 6; ++i) sF[i][tid] = vF[i];
        }
        if (doB) {
            #pragma unroll
            for (int i = 0; i < 4; ++i) sB[i][tid] = vB[i];
        }
        __syncthreads();
    }

    const ChunkIn cin = ins[chunkId];
    int exF[6], exB[4];
    #pragma unroll
    for (int i = 0; i < 6; ++i) exF[i] = (tid > 0) ? max(cin.inLast[i], sF[i][tid - 1]) : cin.inLast[i];
    #pragma unroll
    for (int i = 0; i < 4; ++i) exB[i] = (tid < NTHREADS - 1) ? min(cin.inNext[i], sB[i][tid + 1]) : cin.inNext[i];

    // backward local walk: inclusive next-distances, clamped to 255, packed
    unsigned nd[PER_THREAD];
    {
        int n1 = exB[0], n2 = exB[1], n3 = exB[2], n4 = exB[3];
        #pragma unroll
        for (int j = PER_THREAD - 1; j >= 0; --j) {
            const int p = pk[j] & 3, lc = (pk[j] >> 2) & 3;
            const int pos = posBase + j;
            if (lc == 1) n1 = pos;
            if (lc == 2) n2 = pos;
            if (p  == 1) n3 = pos;
            if (p  == 2) n4 = pos;
            nd[j] = (unsigned)min(n1 - pos, 255)
                  | ((unsigned)min(n2 - pos, 255) << 8)
                  | ((unsigned)min(n3 - pos, 255) << 16)
                  | ((unsigned)min(n4 - pos, 255) << 24);
        }
    }

    const int aT1 = anyFlags[4*seq+0], aT2 = anyFlags[4*seq+1];
    const int aP1 = anyFlags[4*seq+2], aP2 = anyFlags[4*seq+3];

    double sumAdj = 0.0;
    int vcount = 0;
    {
        int lT1 = exF[0], lT2 = exF[1], lP1 = exF[2], lP2 = exF[3], lV1 = exF[4], lV2 = exF[5];
        #pragma unroll
        for (int j = 0; j < PER_THREAD; ++j) {
            const int p = pk[j] & 3, lc = (pk[j] >> 2) & 3;
            const float ce = __uint_as_float(pk[j] & 0xFFFF0000u);
            const bool valid = lc != 3;
            const int pos = posBase + j;
            const int tm = (lT2 > lT1) ? 1 : 0;     // exclusive FSM state
            const int pm = (lV2 > lV1) ? 1 : 0;
            float m = 1.0f;
            if (valid && p == 1 && pm == 0) m *= 100.0f;   // ITP
            if (valid && p == 2 && pm == 1) m *= 100.0f;   // ITP
            if (lc == 1 && tm == 1 && p == 1) m *= 0.1f;
            if (lc == 2 && tm == 0 && p == 2) m *= 0.1f;
            if (lc == 1) lT1 = pos;
            if (lc == 2) lT2 = pos;
            if (p  == 1) lP1 = pos;
            if (p  == 2) lP2 = pos;
            if (valid && p == 1) lV1 = pos;
            if (valid && p == 2) lV2 = pos;

            const int dpT1 = (lT1 >= 0) ? min(pos - lT1, 255) : 255;
            const int dpT2 = (lT2 >= 0) ? min(pos - lT2, 255) : 255;
            const int dpP1 = (lP1 >= 0) ? min(pos - lP1, 255) : 255;
            const int dpP2 = (lP2 >= 0) ? min(pos - lP2, 255) : 255;
            const unsigned ndj = nd[j];
            const int d2t1 = min(dpT1, (int)( ndj        & 255u));
            const int d2t2 = min(dpT2, (int)((ndj >> 8)  & 255u));
            const int d2p1 = min(dpP1, (int)((ndj >> 16) & 255u));
            const int d2p2 = min(dpP2, (int)((ndj >> 24) & 255u));

            if (p == 1) m *= aT1 ? ((d2t1 == 0) ? 0.1f : ((d2t1 <= 5) ? (0.1f + (float)d2t1 * 0.18f) : 10.0f)) : 20.0f;
            if (p == 2) m *= aT2 ? ((d2t2 == 0) ? 0.1f : ((d2t2 <= 5) ? (0.1f + (float)d2t2 * 0.18f) : 10.0f)) : 20.0f;
            if (lc == 1) m *= aP1 ? ((d2p1 > 5) ? fminf(2.0f + (float)(d2p1 - 5) * 0.3f, 8.0f) : 1.0f) : 5.0f;
            if (lc == 2) m *= aP2 ? ((d2p2 > 5) ? fminf(2.0f + (float)(d2p2 - 5) * 0.3f, 8.0f) : 1.0f) : 5.0f;

            sumAdj += (double)(ce * m);
            vcount += valid ? 1 : 0;
        }
    }

    __shared__ double rA[NTHREADS];
    __shared__ double rV[NTHREADS];
    rA[tid] = sumAdj;
    rV[tid] = (double)vcount;
    __syncthreads();
    for (int st = NTHREADS / 2; st > 0; st >>= 1) {
        if (tid < st) { rA[tid] += rA[tid + st]; rV[tid] += rV[tid + st]; }
        __syncthreads();
    }
    if (tid == 0) {
        partials[2 * chunkId + 0] = rA[0];
        partials[2 * chunkId + 1] = rV[0];
    }
}

__global__ __launch_bounds__(NTHREADS) void k4_final(const double* __restrict__ partials,
                                                     float* __restrict__ out) {
    const int tid = threadIdx.x;
    double sA = 0.0, sV = 0.0;
    for (int i = tid; i < NCHUNK; i += NTHREADS) {
        sA += partials[2 * i + 0];
        sV += partials[2 * i + 1];
    }
    __shared__ double rA[NTHREADS];
    __shared__ double rV[NTHREADS];
    rA[tid] = sA; rV[tid] = sV;
    __syncthreads();
    for (int st = NTHREADS / 2; st > 0; st >>= 1) {
        if (tid < st) { rA[tid] += rA[tid + st]; rV[tid] += rV[tid + st]; }
        __syncthreads();
    }
    if (tid == 0) out[0] = (float)(rA[0] / fmax(rV[0], 1.0));
}

extern "C" void kernel_launch(void* const* d_in, const int* in_sizes, int n_in,
                              void* d_out, int out_size, void* d_ws, size_t ws_size,
                              hipStream_t stream) {
    const float* logits = (const float*)d_in[0];
    const int*   labels = (const int*)d_in[1];
    float* out = (float*)d_out;
    char* ws = (char*)d_ws;

    ChunkSum* sums   = (ChunkSum*)(ws + WS_SUMS);
    ChunkIn*  ins    = (ChunkIn*)(ws + WS_INS);
    int*      flags  = (int*)(ws + WS_FLAGS);
    double*   parts  = (double*)(ws + WS_PART);
    unsigned* packed = (unsigned*)(ws + WS_PACKED);

    // No memset needed: every ws region is fully rewritten each call.
    k1_summ<<<NCHUNK, NTHREADS, 0, stream>>>(logits, labels, packed, sums);
    k2_combine<<<1, 64, 0, stream>>>(sums, ins, flags);
    k3_main<<<NCHUNK, NTHREADS, 0, stream>>>(packed, ins, flags, parts);
    k4_final<<<1, NTHREADS, 0, stream>>>(parts, out);
}